// Round 16
// baseline (184.435 us; speedup 1.0000x reference)
//
#include <hip/hip_runtime.h>
#include <hip/hip_bf16.h>

// ---------------------------------------------------------------------------
// GAT 2-layer forward on MI355X.  9 dispatches.
//   k_prep: W split (blocks 0-127) ∥ per-block bucket hist (blocks 128-255,
//           atomic-free bhist[128][256])
//   k_bukscatter: in-block base computation from bhist + coarse scatter
//   k_csr: in-block scan of bcount (cbase = sbase + b*BUK_S) + fine pass
//   per layer: k_gemm (2-term split-bf16 MFMA, fused att dots)
//              k_agg  (fused att-coef + quad-edge uint4 h gather)
//   k_pool_partial + k_pool_final
//   Lessons: no hipMemset (R10); no cross-block-fence fusions (R13); no
//   gemm∥hist co-kernel (R14); shuffles once per node, not per edge (R6).
// ---------------------------------------------------------------------------

#define THREADS 256
#define PSLICE 16
#define BUK_S 196        // nodes per bucket (NBUK = 256 for N=50000)
#define SORT_BLOCKS 128

typedef __attribute__((ext_vector_type(8))) short short8v;   // 8 bf16
typedef __attribute__((ext_vector_type(4))) float f32x4;

static __device__ __forceinline__ unsigned short f2bf(float f) {
    unsigned int u = __float_as_uint(f);
    return (unsigned short)((u + 0x7fffu + ((u >> 16) & 1u)) >> 16);  // RNE
}
static __device__ __forceinline__ float bf2f(unsigned short b) {
    return __uint_as_float(((unsigned int)b) << 16);
}

// ---- prep: W split (blocks 0..127) ∥ per-block bucket hist (128..255) ----
// WB[((c*4+t)*64 + lane)*8 + j] ; value = W[k][n], k=t*32+(lane>>4)*8+j, n=c*16+(lane&15)
__global__ __launch_bounds__(THREADS) void k_prep(const float* __restrict__ W1,
                                                  const float* __restrict__ W2,
                                                  unsigned short* __restrict__ Wh1,
                                                  unsigned short* __restrict__ Wl1,
                                                  unsigned short* __restrict__ Wh2,
                                                  unsigned short* __restrict__ Wl2,
                                                  const int* __restrict__ dst,
                                                  int* __restrict__ bhist,
                                                  int E_, int chunk) {
    int tid = threadIdx.x;
    if ((int)blockIdx.x >= 128) {
        int hb = blockIdx.x - 128;
        __shared__ int hist[THREADS];
        hist[tid] = 0;
        __syncthreads();
        int e0 = hb * chunk;
        int e1 = min(e0 + chunk, E_);
        for (int e = e0 + tid; e < e1; e += THREADS)
            atomicAdd(&hist[dst[e] / BUK_S], 1);
        __syncthreads();
        bhist[hb * THREADS + tid] = hist[tid];
        return;
    }
    int t = blockIdx.x * THREADS + tid;
    const float* W = W1;
    unsigned short* Wh = Wh1;
    unsigned short* Wl = Wl1;
    if (t >= 128 * 128) {
        t -= 128 * 128;
        W = W2; Wh = Wh2; Wl = Wl2;
    }
    int k = t >> 7, n = t & 127;
    float w = W[t];
    unsigned short h = f2bf(w);
    unsigned short lo = f2bf(w - bf2f(h));
    int c = n >> 4, nl = n & 15, tt = k >> 5, kk = k & 31, g = kk >> 3, j = kk & 7;
    int o = (((c * 4 + tt) * 64) + g * 16 + nl) * 8 + j;
    Wh[o] = h;
    Wl[o] = lo;
}

// ---- coarse scatter; each block derives its own per-bucket bases from bhist.
// base[bucket] = excl_scan(colsum)[bucket] + sum of earlier blocks' counts.
// Block 0 also publishes bcount (column sums) for k_csr. ----
__global__ __launch_bounds__(THREADS) void k_bukscatter(const int* __restrict__ src,
                                                        const int* __restrict__ dst,
                                                        const int* __restrict__ bhist,
                                                        int* __restrict__ bcount,
                                                        unsigned int* __restrict__ rec,
                                                        int E_, int chunk) {
    __shared__ int s[THREADS];
    __shared__ int base[THREADS];
    __shared__ int hist[THREADS];
    int tid = threadIdx.x;
    int b = blockIdx.x;
    int tot = 0, mypre = 0;
    #pragma unroll 8
    for (int bb = 0; bb < SORT_BLOCKS; ++bb) {
        int v = bhist[bb * THREADS + tid];
        if (bb < b) mypre += v;
        tot += v;
    }
    if (b == 0) bcount[tid] = tot;
    s[tid] = tot;
    __syncthreads();
    for (int off = 1; off < THREADS; off <<= 1) {
        int t = (tid >= off) ? s[tid - off] : 0;
        __syncthreads();
        s[tid] += t;
        __syncthreads();
    }
    base[tid] = (s[tid] - tot) + mypre;
    hist[tid] = 0;
    __syncthreads();
    int e0 = b * chunk;
    int e1 = min(e0 + chunk, E_);
    for (int e = e0 + tid; e < e1; e += THREADS) {
        int d = dst[e];
        int bk = d / BUK_S;
        int r = atomicAdd(&hist[bk], 1);
        rec[base[bk] + r] = (unsigned int)src[e] | ((unsigned int)(d - bk * BUK_S) << 17);
    }
}

// ---- per-bucket fine pass -> rowptr + esrc (self-loop last slot).
// sbase via in-block scan of bcount; cbase = sbase + b*BUK_S (self-loop
// prefix is linear). ----
__global__ __launch_bounds__(THREADS) void k_csr(const unsigned int* __restrict__ rec,
                                                 const int* __restrict__ bcount,
                                                 int* __restrict__ rowptr,
                                                 int* __restrict__ esrc,
                                                 int Nn, int nbuk, int Etot) {
    __shared__ int sA[THREADS];
    __shared__ int lbc[THREADS];
    __shared__ int cnt[THREADS];
    __shared__ int s[THREADS];
    __shared__ int cur[THREADS];
    int b = blockIdx.x;
    int tid = threadIdx.x;
    int v = (tid < nbuk) ? bcount[tid] : 0;
    lbc[tid] = v;
    sA[tid] = v;
    __syncthreads();
    for (int off = 1; off < THREADS; off <<= 1) {
        int t = (tid >= off) ? sA[tid - off] : 0;
        __syncthreads();
        sA[tid] += t;
        __syncthreads();
    }
    sA[tid] -= v;                   // exclusive scan = sbase[tid]
    __syncthreads();
    int n0 = b * BUK_S;
    int ns = min(BUK_S, Nn - n0);
    int cnt_e = lbc[b];
    int rbase = sA[b];
    int cb = rbase + b * BUK_S;     // cbase

    cnt[tid] = 0;
    __syncthreads();
    for (int i = tid; i < cnt_e; i += THREADS)
        atomicAdd(&cnt[rec[rbase + i] >> 17], 1);
    __syncthreads();
    int w = (tid < ns) ? cnt[tid] + 1 : 0;   // +1 self-loop
    s[tid] = w;
    __syncthreads();
    for (int off = 1; off < THREADS; off <<= 1) {
        int t = (tid >= off) ? s[tid - off] : 0;
        __syncthreads();
        s[tid] += t;
        __syncthreads();
    }
    int excl = s[tid] - w;
    __syncthreads();
    s[tid] = excl;
    cur[tid] = excl;
    if (tid < ns) rowptr[n0 + tid] = cb + excl;
    if (b == nbuk - 1 && tid == 0) rowptr[Nn] = Etot;
    __syncthreads();
    for (int i = tid; i < cnt_e; i += THREADS) {
        unsigned int r = rec[rbase + i];
        int l = r >> 17;
        int slot = atomicAdd(&cur[l], 1);
        esrc[cb + slot] = (int)(r & 0x1FFFFu);
    }
    __syncthreads();
    if (tid < ns) esrc[cb + s[tid] + cnt[tid]] = n0 + tid;   // self-loop last
}

// swizzled LDS index (ushort units) for x tiles
static __device__ __forceinline__ int xsw(int r, int c) {
    return (((r * 16 + (c >> 3)) ^ (r & 7)) << 3) | (c & 7);
}

// H = X(gathered) @ W via MFMA 2-term split-bf16 (xh*Wh + xh*Wl).
// 64 rows x 128 cols per block, 4 waves x 16 rows x 8 col-tiles.
__global__ __launch_bounds__(THREADS) void k_gemm(const float* __restrict__ X,
                                                  const int* __restrict__ idx,
                                                  const unsigned short* __restrict__ WBh,
                                                  const unsigned short* __restrict__ WBl,
                                                  const float* __restrict__ a_s,
                                                  const float* __restrict__ a_d,
                                                  unsigned short* __restrict__ outb,
                                                  float* __restrict__ as_,
                                                  float* __restrict__ ad_, int Nrows) {
    __shared__ unsigned short xh[64 * 128];   // 16 KB

    {
        int r = threadIdx.x >> 2;            // 0..63
        int c0 = (threadIdx.x & 3) * 32;
        int R = blockIdx.x * 64 + r;
        if (R < Nrows) {
            int g = idx ? idx[R] : R;
            const float4* xrow = (const float4*)(X + (size_t)g * 128);
            #pragma unroll
            for (int i = 0; i < 8; ++i) {
                float4 v = xrow[(c0 >> 2) + i];
                ushort4 hh;
                hh.x = f2bf(v.x);
                hh.y = f2bf(v.y);
                hh.z = f2bf(v.z);
                hh.w = f2bf(v.w);
                *(ushort4*)&xh[xsw(r, c0 + i * 4)] = hh;
            }
        } else {
            #pragma unroll
            for (int i = 0; i < 8; ++i)
                *(ushort4*)&xh[xsw(r, c0 + i * 4)] = make_ushort4(0, 0, 0, 0);
        }
    }
    __syncthreads();

    int wid = threadIdx.x >> 6;
    int lane = threadIdx.x & 63;
    int nl = lane & 15;
    int g = lane >> 4;
    int arow = wid * 16 + nl;

    f32x4 acc[8];
    #pragma unroll
    for (int c = 0; c < 8; ++c) acc[c] = (f32x4){0.f, 0.f, 0.f, 0.f};

    #pragma unroll
    for (int t = 0; t < 4; ++t) {
        short8v ah = *(const short8v*)&xh[xsw(arow, t * 32 + g * 8)];
        #pragma unroll
        for (int c = 0; c < 8; ++c) {
            int bo = (((c * 4 + t) * 64) + lane) * 8;
            short8v bh = *(const short8v*)&WBh[bo];
            short8v bl = *(const short8v*)&WBl[bo];
            acc[c] = __builtin_amdgcn_mfma_f32_16x16x32_bf16(ah, bh, acc[c], 0, 0, 0);
            acc[c] = __builtin_amdgcn_mfma_f32_16x16x32_bf16(ah, bl, acc[c], 0, 0, 0);
        }
    }

    float asv[8], adv[8];
    #pragma unroll
    for (int c = 0; c < 8; ++c) {
        asv[c] = a_s[c * 16 + nl];
        adv[c] = a_d[c * 16 + nl];
    }
    int Rb = blockIdx.x * 64 + wid * 16 + g * 4;
    #pragma unroll
    for (int r = 0; r < 4; ++r) {
        int R = Rb + r;
        bool ok = (R < Nrows);
        float ps = 0.f, pd = 0.f;
        #pragma unroll
        for (int c = 0; c < 8; ++c) {
            float v = acc[c][r];
            if (ok) outb[(size_t)R * 128 + c * 16 + nl] = f2bf(v);
            ps = fmaf(v, asv[c], ps);
            pd = fmaf(v, adv[c], pd);
        }
        #pragma unroll
        for (int o = 8; o; o >>= 1) {
            ps += __shfl_xor(ps, o);
            pd += __shfl_xor(pd, o);
        }
        if (ok && nl == 0) {
            as_[R] = ps;
            ad_[R] = pd;
        }
    }
}

// wave per dst node, fused attention-coef + aggregation.
// Quad-edge gathers: 16 lanes x uint4 (8 bf16 dims) per edge, 4 edges per
// wave memory instruction, 8 instrs (32 edges) in flight per batch.
// Reduce across the 4 edge slots via shfl_xor(16)+shfl_xor(32) once per node.
__global__ __launch_bounds__(THREADS) void k_agg(const unsigned short* __restrict__ hb,
                                                 const float* __restrict__ as_,
                                                 const float* __restrict__ ad_,
                                                 const int* __restrict__ rowptr,
                                                 const int* __restrict__ esrc,
                                                 const float* __restrict__ bias,
                                                 float* __restrict__ out, int Nn) {
    __shared__ int2 ep[4][64];
    int w = threadIdx.x >> 6;
    int lane = threadIdx.x & 63;
    int q = lane >> 4;       // edge slot within quad
    int j = lane & 15;       // dim group (8 dims per lane)
    int d = blockIdx.x * 4 + w;
    if (d >= Nn) return;
    int beg = rowptr[d], end = rowptr[d + 1];
    float adv = ad_[d];
    float z = 0.f;
    float a[8] = {0.f, 0.f, 0.f, 0.f, 0.f, 0.f, 0.f, 0.f};
    for (int c0 = beg; c0 < end; c0 += 64) {
        // vectorized p pre-compute for this chunk (one edge per lane)
        int kk = c0 + lane;
        bool ok = (kk < end);
        int sl = esrc[ok ? kk : beg];
        float pv = 0.f;
        if (ok) {
            float e = as_[sl] + adv;
            e = (e > 0.f) ? e : 0.2f * e;
            pv = __expf(e);
        }
        ep[w][lane] = make_int2(sl, __float_as_int(pv));
        int cn = end - c0;
        if (cn > 64) cn = 64;
        for (int k0 = 0; k0 < cn; k0 += 32) {
            int2 ev[8];
            #pragma unroll
            for (int i = 0; i < 8; ++i)
                ev[i] = ep[w][(k0 + 4 * i + q) & 63];   // p=0 past cn
            uint4 hv[8];
            #pragma unroll
            for (int i = 0; i < 8; ++i)
                hv[i] = *(const uint4*)&hb[((size_t)ev[i].x << 7) + j * 8];
            #pragma unroll
            for (int i = 0; i < 8; ++i) {
                float p = __int_as_float(ev[i].y);
                z += p;
                a[0] += p * __uint_as_float(hv[i].x << 16);
                a[1] += p * __uint_as_float(hv[i].x & 0xffff0000u);
                a[2] += p * __uint_as_float(hv[i].y << 16);
                a[3] += p * __uint_as_float(hv[i].y & 0xffff0000u);
                a[4] += p * __uint_as_float(hv[i].z << 16);
                a[5] += p * __uint_as_float(hv[i].z & 0xffff0000u);
                a[6] += p * __uint_as_float(hv[i].w << 16);
                a[7] += p * __uint_as_float(hv[i].w & 0xffff0000u);
            }
        }
    }
    z += __shfl_xor(z, 16);
    z += __shfl_xor(z, 32);
    #pragma unroll
    for (int t = 0; t < 8; ++t) {
        a[t] += __shfl_xor(a[t], 16);
        a[t] += __shfl_xor(a[t], 32);
    }
    if (q == 0) {
        float inv = 1.f / z;
        float4 o1, o2;
        o1.x = fmaxf(a[0] * inv + bias[j * 8 + 0], 0.f);
        o1.y = fmaxf(a[1] * inv + bias[j * 8 + 1], 0.f);
        o1.z = fmaxf(a[2] * inv + bias[j * 8 + 2], 0.f);
        o1.w = fmaxf(a[3] * inv + bias[j * 8 + 3], 0.f);
        o2.x = fmaxf(a[4] * inv + bias[j * 8 + 4], 0.f);
        o2.y = fmaxf(a[5] * inv + bias[j * 8 + 5], 0.f);
        o2.z = fmaxf(a[6] * inv + bias[j * 8 + 6], 0.f);
        o2.w = fmaxf(a[7] * inv + bias[j * 8 + 7], 0.f);
        *(float4*)&out[(size_t)d * 128 + j * 8] = o1;
        *(float4*)&out[(size_t)d * 128 + j * 8 + 4] = o2;
    }
}

// phase 1: grid (G, PSLICE); each block sums a strided slice of graph g's rows
__global__ __launch_bounds__(THREADS) void k_pool_partial(const float* __restrict__ x,
                                                          const int* __restrict__ batch,
                                                          float* __restrict__ part, int Nn) {
    int g = blockIdx.x;
    int s = blockIdx.y;
    int a = 0, b = Nn;
    while (a < b) { int mid = (a + b) >> 1; if (batch[mid] < g) a = mid + 1; else b = mid; }
    int lo = a;
    b = Nn;
    while (a < b) { int mid = (a + b) >> 1; if (batch[mid] < g + 1) a = mid + 1; else b = mid; }
    int hi = a;

    int j = threadIdx.x & 127;
    int half = threadIdx.x >> 7;
    float acc = 0.f;
    for (int n = lo + s * 2 + half; n < hi; n += 2 * PSLICE) acc += x[(size_t)n * 128 + j];
    __shared__ float sred[THREADS];
    sred[threadIdx.x] = acc;
    __syncthreads();
    if (half == 0) part[((size_t)g * PSLICE + s) * 128 + j] = sred[j] + sred[128 + j];
}

// phase 2: one block (128 threads) per graph: reduce partials, mean, logits
__global__ __launch_bounds__(128) void k_pool_final(const float* __restrict__ part,
                                                    const int* __restrict__ batch,
                                                    const float* __restrict__ Wc,
                                                    const float* __restrict__ bc,
                                                    float* __restrict__ out, int Nn, int Gn) {
    int g = blockIdx.x;
    int j = threadIdx.x;
    int a = 0, b = Nn;
    while (a < b) { int mid = (a + b) >> 1; if (batch[mid] < g) a = mid + 1; else b = mid; }
    int lo = a;
    b = Nn;
    while (a < b) { int mid = (a + b) >> 1; if (batch[mid] < g + 1) a = mid + 1; else b = mid; }
    int cnt = a - lo;

    float s = 0.f;
    #pragma unroll
    for (int t = 0; t < PSLICE; ++t) s += part[((size_t)g * PSLICE + t) * 128 + j];
    float mean = s / fmaxf((float)cnt, 1.f);
    out[Gn + (size_t)g * 128 + j] = mean;

    __shared__ float sred[128];
    sred[j] = mean * Wc[j];
    __syncthreads();
    for (int off = 64; off >= 1; off >>= 1) {
        if (j < off) sred[j] += sred[j + off];
        __syncthreads();
    }
    if (j == 0) out[g] = sred[0] + bc[0];
}

static inline size_t align256(size_t x) { return (x + 255) & ~(size_t)255; }

extern "C" void kernel_launch(void* const* d_in, const int* in_sizes, int n_in,
                              void* d_out, int out_size, void* d_ws, size_t ws_size,
                              hipStream_t stream) {
    const int* x_lex = (const int*)d_in[0];
    const int* eidx  = (const int*)d_in[1];
    const int* batch = (const int*)d_in[2];
    const float* emb = (const float*)d_in[3];
    const float* W1  = (const float*)d_in[4];
    const float* a_s1 = (const float*)d_in[5];
    const float* a_d1 = (const float*)d_in[6];
    const float* b1  = (const float*)d_in[7];
    const float* W2  = (const float*)d_in[8];
    const float* a_s2 = (const float*)d_in[9];
    const float* a_d2 = (const float*)d_in[10];
    const float* b2  = (const float*)d_in[11];
    const float* Wc  = (const float*)d_in[12];
    const float* bc  = (const float*)d_in[13];

    const int N = in_sizes[0];
    const int E = in_sizes[1] / 2;
    const int G = out_size / 129;      // out = [G logits] + [G x 128 pool]
    const int Etot = E + N;
    const int* esrc_in = eidx;
    const int* edst_in = eidx + E;
    const int NBUK = (N + BUK_S - 1) / BUK_S;   // 256 for N=50000

    // workspace carve
    char* p = (char*)d_ws;
    unsigned short* hb = (unsigned short*)p;  p += align256((size_t)N * 128 * 2);
    float* obuf = (float*)p;            p += align256((size_t)N * 128 * 4);
    float* as_  = (float*)p;            p += align256((size_t)N * 4);
    float* ad_  = (float*)p;            p += align256((size_t)N * 4);
    int* bhist  = (int*)p;              p += align256((size_t)SORT_BLOCKS * THREADS * 4);
    int* bcount = (int*)p;              p += align256((size_t)THREADS * 4);
    int* rowptr = (int*)p;              p += align256((size_t)(N + 1) * 4);
    unsigned int* rec = (unsigned int*)p; p += align256((size_t)Etot * 4);
    int* esrc   = (int*)p;              p += align256((size_t)Etot * 4);
    float* part = (float*)p;            p += align256((size_t)G * PSLICE * 128 * 4);
    unsigned short* WBh1 = (unsigned short*)p; p += align256((size_t)128 * 128 * 2);
    unsigned short* WBl1 = (unsigned short*)p; p += align256((size_t)128 * 128 * 2);
    unsigned short* WBh2 = (unsigned short*)p; p += align256((size_t)128 * 128 * 2);
    unsigned short* WBl2 = (unsigned short*)p; p += align256((size_t)128 * 128 * 2);

    const int chunk = (E + SORT_BLOCKS - 1) / SORT_BLOCKS;
    const int gemm_grid = (N + 63) / 64;
    const int agg_grid = (N + 3) / 4;

    // 1. prep: W split ∥ bucket hist
    k_prep<<<128 + SORT_BLOCKS, THREADS, 0, stream>>>(W1, W2, WBh1, WBl1, WBh2, WBl2,
                                                      edst_in, bhist, E, chunk);

    // 2-3. CSR build
    k_bukscatter<<<SORT_BLOCKS, THREADS, 0, stream>>>(esrc_in, edst_in, bhist, bcount, rec, E, chunk);
    k_csr<<<NBUK, THREADS, 0, stream>>>(rec, bcount, rowptr, esrc, N, NBUK, Etot);

    // 4-5. layer 1
    k_gemm<<<gemm_grid, THREADS, 0, stream>>>(emb, x_lex, WBh1, WBl1, a_s1, a_d1, hb, as_, ad_, N);
    k_agg<<<agg_grid, THREADS, 0, stream>>>(hb, as_, ad_, rowptr, esrc, b1, obuf, N);

    // 6-7. layer 2
    k_gemm<<<gemm_grid, THREADS, 0, stream>>>(obuf, nullptr, WBh2, WBl2, a_s2, a_d2, hb, as_, ad_, N);
    k_agg<<<agg_grid, THREADS, 0, stream>>>(hb, as_, ad_, rowptr, esrc, b2, obuf, N);

    // 8-9. pool + logits
    k_pool_partial<<<dim3(G, PSLICE), THREADS, 0, stream>>>(obuf, batch, part, N);
    k_pool_final<<<G, 128, 0, stream>>>(part, batch, Wc, bc, (float*)d_out, N, G);
}

// Round 17
// 168.615 us; speedup vs baseline: 1.0938x; 1.0938x over previous
//
#include <hip/hip_runtime.h>
#include <hip/hip_bf16.h>

// ---------------------------------------------------------------------------
// GAT 2-layer forward on MI355X.  9 dispatches.
//   k_prep: W split (blocks 0-127) ∥ per-block bucket hist (blocks 128-255,
//           atomic-free bhist[128][256])
//   k_bukscatter: in-block base computation from bhist + coarse scatter
//   k_csr: in-block scan of bcount (cbase = sbase + b*BUK_S) + fine pass
//   per layer: k_gemm (2-term split-bf16 MFMA, fused att dots)
//              k_agg  (fused att-coef + PAIRED-edge uint2 h gather — R16's
//              quad-edge variant dropped occupancy 64->34% and regressed)
//   k_pool_partial + k_pool_final
//   Lessons: no hipMemset (R10); no cross-block-fence fusions (R13); no
//   gemm∥hist co-kernel (R14); shuffles once per node (R6); keep agg VGPR
//   low — concurrency comes from waves, not wider per-wave MLP (R16).
// ---------------------------------------------------------------------------

#define THREADS 256
#define PSLICE 16
#define BUK_S 196        // nodes per bucket (NBUK = 256 for N=50000)
#define SORT_BLOCKS 128

typedef __attribute__((ext_vector_type(8))) short short8v;   // 8 bf16
typedef __attribute__((ext_vector_type(4))) float f32x4;

static __device__ __forceinline__ unsigned short f2bf(float f) {
    unsigned int u = __float_as_uint(f);
    return (unsigned short)((u + 0x7fffu + ((u >> 16) & 1u)) >> 16);  // RNE
}
static __device__ __forceinline__ float bf2f(unsigned short b) {
    return __uint_as_float(((unsigned int)b) << 16);
}

// ---- prep: W split (blocks 0..127) ∥ per-block bucket hist (128..255) ----
// WB[((c*4+t)*64 + lane)*8 + j] ; value = W[k][n], k=t*32+(lane>>4)*8+j, n=c*16+(lane&15)
__global__ __launch_bounds__(THREADS) void k_prep(const float* __restrict__ W1,
                                                  const float* __restrict__ W2,
                                                  unsigned short* __restrict__ Wh1,
                                                  unsigned short* __restrict__ Wl1,
                                                  unsigned short* __restrict__ Wh2,
                                                  unsigned short* __restrict__ Wl2,
                                                  const int* __restrict__ dst,
                                                  int* __restrict__ bhist,
                                                  int E_, int chunk) {
    int tid = threadIdx.x;
    if ((int)blockIdx.x >= 128) {
        int hb = blockIdx.x - 128;
        __shared__ int hist[THREADS];
        hist[tid] = 0;
        __syncthreads();
        int e0 = hb * chunk;
        int e1 = min(e0 + chunk, E_);
        for (int e = e0 + tid; e < e1; e += THREADS)
            atomicAdd(&hist[dst[e] / BUK_S], 1);
        __syncthreads();
        bhist[hb * THREADS + tid] = hist[tid];
        return;
    }
    int t = blockIdx.x * THREADS + tid;
    const float* W = W1;
    unsigned short* Wh = Wh1;
    unsigned short* Wl = Wl1;
    if (t >= 128 * 128) {
        t -= 128 * 128;
        W = W2; Wh = Wh2; Wl = Wl2;
    }
    int k = t >> 7, n = t & 127;
    float w = W[t];
    unsigned short h = f2bf(w);
    unsigned short lo = f2bf(w - bf2f(h));
    int c = n >> 4, nl = n & 15, tt = k >> 5, kk = k & 31, g = kk >> 3, j = kk & 7;
    int o = (((c * 4 + tt) * 64) + g * 16 + nl) * 8 + j;
    Wh[o] = h;
    Wl[o] = lo;
}

// ---- coarse scatter; each block derives its own per-bucket bases from bhist.
// base[bucket] = excl_scan(colsum)[bucket] + sum of earlier blocks' counts.
// Block 0 also publishes bcount (column sums) for k_csr. ----
__global__ __launch_bounds__(THREADS) void k_bukscatter(const int* __restrict__ src,
                                                        const int* __restrict__ dst,
                                                        const int* __restrict__ bhist,
                                                        int* __restrict__ bcount,
                                                        unsigned int* __restrict__ rec,
                                                        int E_, int chunk) {
    __shared__ int s[THREADS];
    __shared__ int base[THREADS];
    __shared__ int hist[THREADS];
    int tid = threadIdx.x;
    int b = blockIdx.x;
    int tot = 0, mypre = 0;
    #pragma unroll 8
    for (int bb = 0; bb < SORT_BLOCKS; ++bb) {
        int v = bhist[bb * THREADS + tid];
        if (bb < b) mypre += v;
        tot += v;
    }
    if (b == 0) bcount[tid] = tot;
    s[tid] = tot;
    __syncthreads();
    for (int off = 1; off < THREADS; off <<= 1) {
        int t = (tid >= off) ? s[tid - off] : 0;
        __syncthreads();
        s[tid] += t;
        __syncthreads();
    }
    base[tid] = (s[tid] - tot) + mypre;
    hist[tid] = 0;
    __syncthreads();
    int e0 = b * chunk;
    int e1 = min(e0 + chunk, E_);
    for (int e = e0 + tid; e < e1; e += THREADS) {
        int d = dst[e];
        int bk = d / BUK_S;
        int r = atomicAdd(&hist[bk], 1);
        rec[base[bk] + r] = (unsigned int)src[e] | ((unsigned int)(d - bk * BUK_S) << 17);
    }
}

// ---- per-bucket fine pass -> rowptr + esrc (self-loop last slot).
// sbase via in-block scan of bcount; cbase = sbase + b*BUK_S. ----
__global__ __launch_bounds__(THREADS) void k_csr(const unsigned int* __restrict__ rec,
                                                 const int* __restrict__ bcount,
                                                 int* __restrict__ rowptr,
                                                 int* __restrict__ esrc,
                                                 int Nn, int nbuk, int Etot) {
    __shared__ int sA[THREADS];
    __shared__ int lbc[THREADS];
    __shared__ int cnt[THREADS];
    __shared__ int s[THREADS];
    __shared__ int cur[THREADS];
    int b = blockIdx.x;
    int tid = threadIdx.x;
    int v = (tid < nbuk) ? bcount[tid] : 0;
    lbc[tid] = v;
    sA[tid] = v;
    __syncthreads();
    for (int off = 1; off < THREADS; off <<= 1) {
        int t = (tid >= off) ? sA[tid - off] : 0;
        __syncthreads();
        sA[tid] += t;
        __syncthreads();
    }
    sA[tid] -= v;                   // exclusive scan = sbase[tid]
    __syncthreads();
    int n0 = b * BUK_S;
    int ns = min(BUK_S, Nn - n0);
    int cnt_e = lbc[b];
    int rbase = sA[b];
    int cb = rbase + b * BUK_S;     // cbase

    cnt[tid] = 0;
    __syncthreads();
    for (int i = tid; i < cnt_e; i += THREADS)
        atomicAdd(&cnt[rec[rbase + i] >> 17], 1);
    __syncthreads();
    int w = (tid < ns) ? cnt[tid] + 1 : 0;   // +1 self-loop
    s[tid] = w;
    __syncthreads();
    for (int off = 1; off < THREADS; off <<= 1) {
        int t = (tid >= off) ? s[tid - off] : 0;
        __syncthreads();
        s[tid] += t;
        __syncthreads();
    }
    int excl = s[tid] - w;
    __syncthreads();
    s[tid] = excl;
    cur[tid] = excl;
    if (tid < ns) rowptr[n0 + tid] = cb + excl;
    if (b == nbuk - 1 && tid == 0) rowptr[Nn] = Etot;
    __syncthreads();
    for (int i = tid; i < cnt_e; i += THREADS) {
        unsigned int r = rec[rbase + i];
        int l = r >> 17;
        int slot = atomicAdd(&cur[l], 1);
        esrc[cb + slot] = (int)(r & 0x1FFFFu);
    }
    __syncthreads();
    if (tid < ns) esrc[cb + s[tid] + cnt[tid]] = n0 + tid;   // self-loop last
}

// swizzled LDS index (ushort units) for x tiles
static __device__ __forceinline__ int xsw(int r, int c) {
    return (((r * 16 + (c >> 3)) ^ (r & 7)) << 3) | (c & 7);
}

// H = X(gathered) @ W via MFMA 2-term split-bf16 (xh*Wh + xh*Wl).
// 64 rows x 128 cols per block, 4 waves x 16 rows x 8 col-tiles.
__global__ __launch_bounds__(THREADS) void k_gemm(const float* __restrict__ X,
                                                  const int* __restrict__ idx,
                                                  const unsigned short* __restrict__ WBh,
                                                  const unsigned short* __restrict__ WBl,
                                                  const float* __restrict__ a_s,
                                                  const float* __restrict__ a_d,
                                                  unsigned short* __restrict__ outb,
                                                  float* __restrict__ as_,
                                                  float* __restrict__ ad_, int Nrows) {
    __shared__ unsigned short xh[64 * 128];   // 16 KB

    {
        int r = threadIdx.x >> 2;            // 0..63
        int c0 = (threadIdx.x & 3) * 32;
        int R = blockIdx.x * 64 + r;
        if (R < Nrows) {
            int g = idx ? idx[R] : R;
            const float4* xrow = (const float4*)(X + (size_t)g * 128);
            #pragma unroll
            for (int i = 0; i < 8; ++i) {
                float4 v = xrow[(c0 >> 2) + i];
                ushort4 hh;
                hh.x = f2bf(v.x);
                hh.y = f2bf(v.y);
                hh.z = f2bf(v.z);
                hh.w = f2bf(v.w);
                *(ushort4*)&xh[xsw(r, c0 + i * 4)] = hh;
            }
        } else {
            #pragma unroll
            for (int i = 0; i < 8; ++i)
                *(ushort4*)&xh[xsw(r, c0 + i * 4)] = make_ushort4(0, 0, 0, 0);
        }
    }
    __syncthreads();

    int wid = threadIdx.x >> 6;
    int lane = threadIdx.x & 63;
    int nl = lane & 15;
    int g = lane >> 4;
    int arow = wid * 16 + nl;

    f32x4 acc[8];
    #pragma unroll
    for (int c = 0; c < 8; ++c) acc[c] = (f32x4){0.f, 0.f, 0.f, 0.f};

    #pragma unroll
    for (int t = 0; t < 4; ++t) {
        short8v ah = *(const short8v*)&xh[xsw(arow, t * 32 + g * 8)];
        #pragma unroll
        for (int c = 0; c < 8; ++c) {
            int bo = (((c * 4 + t) * 64) + lane) * 8;
            short8v bh = *(const short8v*)&WBh[bo];
            short8v bl = *(const short8v*)&WBl[bo];
            acc[c] = __builtin_amdgcn_mfma_f32_16x16x32_bf16(ah, bh, acc[c], 0, 0, 0);
            acc[c] = __builtin_amdgcn_mfma_f32_16x16x32_bf16(ah, bl, acc[c], 0, 0, 0);
        }
    }

    float asv[8], adv[8];
    #pragma unroll
    for (int c = 0; c < 8; ++c) {
        asv[c] = a_s[c * 16 + nl];
        adv[c] = a_d[c * 16 + nl];
    }
    int Rb = blockIdx.x * 64 + wid * 16 + g * 4;
    #pragma unroll
    for (int r = 0; r < 4; ++r) {
        int R = Rb + r;
        bool ok = (R < Nrows);
        float ps = 0.f, pd = 0.f;
        #pragma unroll
        for (int c = 0; c < 8; ++c) {
            float v = acc[c][r];
            if (ok) outb[(size_t)R * 128 + c * 16 + nl] = f2bf(v);
            ps = fmaf(v, asv[c], ps);
            pd = fmaf(v, adv[c], pd);
        }
        #pragma unroll
        for (int o = 8; o; o >>= 1) {
            ps += __shfl_xor(ps, o);
            pd += __shfl_xor(pd, o);
        }
        if (ok && nl == 0) {
            as_[R] = ps;
            ad_[R] = pd;
        }
    }
}

// wave per dst node, fused attention-coef + aggregation (R15 form).
// Per 64-edge chunk: lane j computes p for edge c0+j, stores (src,p) to
// per-wave LDS; gather loop: 32 lanes x uint2 (4 bf16 dims) per edge,
// 2 edges per wave memory instr, 8 loads in flight. shfl_xor(32) combine.
__global__ __launch_bounds__(THREADS) void k_agg(const unsigned short* __restrict__ hb,
                                                 const float* __restrict__ as_,
                                                 const float* __restrict__ ad_,
                                                 const int* __restrict__ rowptr,
                                                 const int* __restrict__ esrc,
                                                 const float* __restrict__ bias,
                                                 float* __restrict__ out, int Nn) {
    __shared__ int2 ep[4][64];
    int w = threadIdx.x >> 6;
    int lane = threadIdx.x & 63;
    int half = lane >> 5;    // which edge of the pair
    int j = lane & 31;       // dim group (4 dims per lane)
    int d = blockIdx.x * 4 + w;
    if (d >= Nn) return;
    int beg = rowptr[d], end = rowptr[d + 1];
    float adv = ad_[d];
    float z = 0.f, a0 = 0.f, a1 = 0.f, a2 = 0.f, a3 = 0.f;
    for (int c0 = beg; c0 < end; c0 += 64) {
        int kk = c0 + lane;
        bool ok = (kk < end);
        int sl = esrc[ok ? kk : beg];
        float pv = 0.f;
        if (ok) {
            float e = as_[sl] + adv;
            e = (e > 0.f) ? e : 0.2f * e;
            pv = __expf(e);
        }
        ep[w][lane] = make_int2(sl, __float_as_int(pv));
        int cn = end - c0;
        if (cn > 64) cn = 64;
        for (int k0 = 0; k0 < cn; k0 += 16) {
            int2 ev[8];
            #pragma unroll
            for (int i = 0; i < 8; ++i)
                ev[i] = ep[w][(k0 + 2 * i + half) & 63];   // p=0 past cn
            uint2 hv[8];
            #pragma unroll
            for (int i = 0; i < 8; ++i)
                hv[i] = *(const uint2*)&hb[((size_t)ev[i].x << 7) + j * 4];
            #pragma unroll
            for (int i = 0; i < 8; ++i) {
                float p = __int_as_float(ev[i].y);
                z += p;
                a0 += p * __uint_as_float(hv[i].x << 16);
                a1 += p * __uint_as_float(hv[i].x & 0xffff0000u);
                a2 += p * __uint_as_float(hv[i].y << 16);
                a3 += p * __uint_as_float(hv[i].y & 0xffff0000u);
            }
        }
    }
    z  += __shfl_xor(z, 32);
    a0 += __shfl_xor(a0, 32);
    a1 += __shfl_xor(a1, 32);
    a2 += __shfl_xor(a2, 32);
    a3 += __shfl_xor(a3, 32);
    if (half == 0) {
        float inv = 1.f / z;
        float4 o;
        o.x = fmaxf(a0 * inv + bias[j * 4 + 0], 0.f);
        o.y = fmaxf(a1 * inv + bias[j * 4 + 1], 0.f);
        o.z = fmaxf(a2 * inv + bias[j * 4 + 2], 0.f);
        o.w = fmaxf(a3 * inv + bias[j * 4 + 3], 0.f);
        *(float4*)&out[(size_t)d * 128 + j * 4] = o;
    }
}

// phase 1: grid (G, PSLICE); each block sums a strided slice of graph g's rows
__global__ __launch_bounds__(THREADS) void k_pool_partial(const float* __restrict__ x,
                                                          const int* __restrict__ batch,
                                                          float* __restrict__ part, int Nn) {
    int g = blockIdx.x;
    int s = blockIdx.y;
    int a = 0, b = Nn;
    while (a < b) { int mid = (a + b) >> 1; if (batch[mid] < g) a = mid + 1; else b = mid; }
    int lo = a;
    b = Nn;
    while (a < b) { int mid = (a + b) >> 1; if (batch[mid] < g + 1) a = mid + 1; else b = mid; }
    int hi = a;

    int j = threadIdx.x & 127;
    int half = threadIdx.x >> 7;
    float acc = 0.f;
    for (int n = lo + s * 2 + half; n < hi; n += 2 * PSLICE) acc += x[(size_t)n * 128 + j];
    __shared__ float sred[THREADS];
    sred[threadIdx.x] = acc;
    __syncthreads();
    if (half == 0) part[((size_t)g * PSLICE + s) * 128 + j] = sred[j] + sred[128 + j];
}

// phase 2: one block (128 threads) per graph: reduce partials, mean, logits
__global__ __launch_bounds__(128) void k_pool_final(const float* __restrict__ part,
                                                    const int* __restrict__ batch,
                                                    const float* __restrict__ Wc,
                                                    const float* __restrict__ bc,
                                                    float* __restrict__ out, int Nn, int Gn) {
    int g = blockIdx.x;
    int j = threadIdx.x;
    int a = 0, b = Nn;
    while (a < b) { int mid = (a + b) >> 1; if (batch[mid] < g) a = mid + 1; else b = mid; }
    int lo = a;
    b = Nn;
    while (a < b) { int mid = (a + b) >> 1; if (batch[mid] < g + 1) a = mid + 1; else b = mid; }
    int cnt = a - lo;

    float s = 0.f;
    #pragma unroll
    for (int t = 0; t < PSLICE; ++t) s += part[((size_t)g * PSLICE + t) * 128 + j];
    float mean = s / fmaxf((float)cnt, 1.f);
    out[Gn + (size_t)g * 128 + j] = mean;

    __shared__ float sred[128];
    sred[j] = mean * Wc[j];
    __syncthreads();
    for (int off = 64; off >= 1; off >>= 1) {
        if (j < off) sred[j] += sred[j + off];
        __syncthreads();
    }
    if (j == 0) out[g] = sred[0] + bc[0];
}

static inline size_t align256(size_t x) { return (x + 255) & ~(size_t)255; }

extern "C" void kernel_launch(void* const* d_in, const int* in_sizes, int n_in,
                              void* d_out, int out_size, void* d_ws, size_t ws_size,
                              hipStream_t stream) {
    const int* x_lex = (const int*)d_in[0];
    const int* eidx  = (const int*)d_in[1];
    const int* batch = (const int*)d_in[2];
    const float* emb = (const float*)d_in[3];
    const float* W1  = (const float*)d_in[4];
    const float* a_s1 = (const float*)d_in[5];
    const float* a_d1 = (const float*)d_in[6];
    const float* b1  = (const float*)d_in[7];
    const float* W2  = (const float*)d_in[8];
    const float* a_s2 = (const float*)d_in[9];
    const float* a_d2 = (const float*)d_in[10];
    const float* b2  = (const float*)d_in[11];
    const float* Wc  = (const float*)d_in[12];
    const float* bc  = (const float*)d_in[13];

    const int N = in_sizes[0];
    const int E = in_sizes[1] / 2;
    const int G = out_size / 129;      // out = [G logits] + [G x 128 pool]
    const int Etot = E + N;
    const int* esrc_in = eidx;
    const int* edst_in = eidx + E;
    const int NBUK = (N + BUK_S - 1) / BUK_S;   // 256 for N=50000

    // workspace carve
    char* p = (char*)d_ws;
    unsigned short* hb = (unsigned short*)p;  p += align256((size_t)N * 128 * 2);
    float* obuf = (float*)p;            p += align256((size_t)N * 128 * 4);
    float* as_  = (float*)p;            p += align256((size_t)N * 4);
    float* ad_  = (float*)p;            p += align256((size_t)N * 4);
    int* bhist  = (int*)p;              p += align256((size_t)SORT_BLOCKS * THREADS * 4);
    int* bcount = (int*)p;              p += align256((size_t)THREADS * 4);
    int* rowptr = (int*)p;              p += align256((size_t)(N + 1) * 4);
    unsigned int* rec = (unsigned int*)p; p += align256((size_t)Etot * 4);
    int* esrc   = (int*)p;              p += align256((size_t)Etot * 4);
    float* part = (float*)p;            p += align256((size_t)G * PSLICE * 128 * 4);
    unsigned short* WBh1 = (unsigned short*)p; p += align256((size_t)128 * 128 * 2);
    unsigned short* WBl1 = (unsigned short*)p; p += align256((size_t)128 * 128 * 2);
    unsigned short* WBh2 = (unsigned short*)p; p += align256((size_t)128 * 128 * 2);
    unsigned short* WBl2 = (unsigned short*)p; p += align256((size_t)128 * 128 * 2);

    const int chunk = (E + SORT_BLOCKS - 1) / SORT_BLOCKS;
    const int gemm_grid = (N + 63) / 64;
    const int agg_grid = (N + 3) / 4;

    // 1. prep: W split ∥ bucket hist
    k_prep<<<128 + SORT_BLOCKS, THREADS, 0, stream>>>(W1, W2, WBh1, WBl1, WBh2, WBl2,
                                                      edst_in, bhist, E, chunk);

    // 2-3. CSR build
    k_bukscatter<<<SORT_BLOCKS, THREADS, 0, stream>>>(esrc_in, edst_in, bhist, bcount, rec, E, chunk);
    k_csr<<<NBUK, THREADS, 0, stream>>>(rec, bcount, rowptr, esrc, N, NBUK, Etot);

    // 4-5. layer 1
    k_gemm<<<gemm_grid, THREADS, 0, stream>>>(emb, x_lex, WBh1, WBl1, a_s1, a_d1, hb, as_, ad_, N);
    k_agg<<<agg_grid, THREADS, 0, stream>>>(hb, as_, ad_, rowptr, esrc, b1, obuf, N);

    // 6-7. layer 2
    k_gemm<<<gemm_grid, THREADS, 0, stream>>>(obuf, nullptr, WBh2, WBl2, a_s2, a_d2, hb, as_, ad_, N);
    k_agg<<<agg_grid, THREADS, 0, stream>>>(hb, as_, ad_, rowptr, esrc, b2, obuf, N);

    // 8-9. pool + logits
    k_pool_partial<<<dim3(G, PSLICE), THREADS, 0, stream>>>(obuf, batch, part, N);
    k_pool_final<<<G, 128, 0, stream>>>(part, batch, Wc, bc, (float*)d_out, N, G);
}

// Round 18
// 162.617 us; speedup vs baseline: 1.1342x; 1.0369x over previous
//
#include <hip/hip_runtime.h>
#include <hip/hip_bf16.h>

// ---------------------------------------------------------------------------
// GAT 2-layer forward on MI355X.  8 dispatches.
//   k_prep: W split (blocks 0-127) ∥ per-block bucket hist (blocks 128-255)
//   k_bukscatter: in-block base computation from bhist + coarse scatter
//   k_gemm_csr: layer-1 gemm (blocks < gemm_grid) ∥ k_csr body (blocks after;
//               independent chains, LDS aliased, no fences/atomics-global)
//   k_agg (fused att-coef + paired-edge uint2 h gather)
//   k_gemm: layer-2 gemm ; k_agg
//   k_pool_partial + k_pool_final
//   Lessons: no hipMemset (R10); no cross-block-fence fusions (R13); no
//   shared-dispatch work with global atomics/spins (R14); shuffles once per
//   node (R6); keep agg VGPR low (R16); agg plateaued at ~2.4-2.7 TB/s
//   random-gather — treated as roofline.
// ---------------------------------------------------------------------------

#define THREADS 256
#define PSLICE 16
#define BUK_S 196        // nodes per bucket (NBUK = 256 for N=50000)
#define SORT_BLOCKS 128

typedef __attribute__((ext_vector_type(8))) short short8v;   // 8 bf16
typedef __attribute__((ext_vector_type(4))) float f32x4;

static __device__ __forceinline__ unsigned short f2bf(float f) {
    unsigned int u = __float_as_uint(f);
    return (unsigned short)((u + 0x7fffu + ((u >> 16) & 1u)) >> 16);  // RNE
}
static __device__ __forceinline__ float bf2f(unsigned short b) {
    return __uint_as_float(((unsigned int)b) << 16);
}

// ---- prep: W split (blocks 0..127) ∥ per-block bucket hist (128..255) ----
__global__ __launch_bounds__(THREADS) void k_prep(const float* __restrict__ W1,
                                                  const float* __restrict__ W2,
                                                  unsigned short* __restrict__ Wh1,
                                                  unsigned short* __restrict__ Wl1,
                                                  unsigned short* __restrict__ Wh2,
                                                  unsigned short* __restrict__ Wl2,
                                                  const int* __restrict__ dst,
                                                  int* __restrict__ bhist,
                                                  int E_, int chunk) {
    int tid = threadIdx.x;
    if ((int)blockIdx.x >= 128) {
        int hb = blockIdx.x - 128;
        __shared__ int hist[THREADS];
        hist[tid] = 0;
        __syncthreads();
        int e0 = hb * chunk;
        int e1 = min(e0 + chunk, E_);
        for (int e = e0 + tid; e < e1; e += THREADS)
            atomicAdd(&hist[dst[e] / BUK_S], 1);
        __syncthreads();
        bhist[hb * THREADS + tid] = hist[tid];
        return;
    }
    int t = blockIdx.x * THREADS + tid;
    const float* W = W1;
    unsigned short* Wh = Wh1;
    unsigned short* Wl = Wl1;
    if (t >= 128 * 128) {
        t -= 128 * 128;
        W = W2; Wh = Wh2; Wl = Wl2;
    }
    int k = t >> 7, n = t & 127;
    float w = W[t];
    unsigned short h = f2bf(w);
    unsigned short lo = f2bf(w - bf2f(h));
    int c = n >> 4, nl = n & 15, tt = k >> 5, kk = k & 31, g = kk >> 3, j = kk & 7;
    int o = (((c * 4 + tt) * 64) + g * 16 + nl) * 8 + j;
    Wh[o] = h;
    Wl[o] = lo;
}

// ---- coarse scatter; per-block bases derived from bhist in-block ----
__global__ __launch_bounds__(THREADS) void k_bukscatter(const int* __restrict__ src,
                                                        const int* __restrict__ dst,
                                                        const int* __restrict__ bhist,
                                                        int* __restrict__ bcount,
                                                        unsigned int* __restrict__ rec,
                                                        int E_, int chunk) {
    __shared__ int s[THREADS];
    __shared__ int base[THREADS];
    __shared__ int hist[THREADS];
    int tid = threadIdx.x;
    int b = blockIdx.x;
    int tot = 0, mypre = 0;
    #pragma unroll 8
    for (int bb = 0; bb < SORT_BLOCKS; ++bb) {
        int v = bhist[bb * THREADS + tid];
        if (bb < b) mypre += v;
        tot += v;
    }
    if (b == 0) bcount[tid] = tot;
    s[tid] = tot;
    __syncthreads();
    for (int off = 1; off < THREADS; off <<= 1) {
        int t = (tid >= off) ? s[tid - off] : 0;
        __syncthreads();
        s[tid] += t;
        __syncthreads();
    }
    base[tid] = (s[tid] - tot) + mypre;
    hist[tid] = 0;
    __syncthreads();
    int e0 = b * chunk;
    int e1 = min(e0 + chunk, E_);
    for (int e = e0 + tid; e < e1; e += THREADS) {
        int d = dst[e];
        int bk = d / BUK_S;
        int r = atomicAdd(&hist[bk], 1);
        rec[base[bk] + r] = (unsigned int)src[e] | ((unsigned int)(d - bk * BUK_S) << 17);
    }
}

// swizzled LDS index (ushort units) for x tiles
static __device__ __forceinline__ int xsw(int r, int c) {
    return (((r * 16 + (c >> 3)) ^ (r & 7)) << 3) | (c & 7);
}

// ---- shared gemm body: H = X(gathered) @ W, 2-term split-bf16 MFMA ----
static __device__ __forceinline__ void gemm_body(unsigned short* xh,
                                                 const float* __restrict__ X,
                                                 const int* __restrict__ idx,
                                                 const unsigned short* __restrict__ WBh,
                                                 const unsigned short* __restrict__ WBl,
                                                 const float* __restrict__ a_s,
                                                 const float* __restrict__ a_d,
                                                 unsigned short* __restrict__ outb,
                                                 float* __restrict__ as_,
                                                 float* __restrict__ ad_,
                                                 int Nrows, int bid) {
    {
        int r = threadIdx.x >> 2;            // 0..63
        int c0 = (threadIdx.x & 3) * 32;
        int R = bid * 64 + r;
        if (R < Nrows) {
            int g = idx ? idx[R] : R;
            const float4* xrow = (const float4*)(X + (size_t)g * 128);
            #pragma unroll
            for (int i = 0; i < 8; ++i) {
                float4 v = xrow[(c0 >> 2) + i];
                ushort4 hh;
                hh.x = f2bf(v.x);
                hh.y = f2bf(v.y);
                hh.z = f2bf(v.z);
                hh.w = f2bf(v.w);
                *(ushort4*)&xh[xsw(r, c0 + i * 4)] = hh;
            }
        } else {
            #pragma unroll
            for (int i = 0; i < 8; ++i)
                *(ushort4*)&xh[xsw(r, c0 + i * 4)] = make_ushort4(0, 0, 0, 0);
        }
    }
    __syncthreads();

    int wid = threadIdx.x >> 6;
    int lane = threadIdx.x & 63;
    int nl = lane & 15;
    int g = lane >> 4;
    int arow = wid * 16 + nl;

    f32x4 acc[8];
    #pragma unroll
    for (int c = 0; c < 8; ++c) acc[c] = (f32x4){0.f, 0.f, 0.f, 0.f};

    #pragma unroll
    for (int t = 0; t < 4; ++t) {
        short8v ah = *(const short8v*)&xh[xsw(arow, t * 32 + g * 8)];
        #pragma unroll
        for (int c = 0; c < 8; ++c) {
            int bo = (((c * 4 + t) * 64) + lane) * 8;
            short8v bh = *(const short8v*)&WBh[bo];
            short8v bl = *(const short8v*)&WBl[bo];
            acc[c] = __builtin_amdgcn_mfma_f32_16x16x32_bf16(ah, bh, acc[c], 0, 0, 0);
            acc[c] = __builtin_amdgcn_mfma_f32_16x16x32_bf16(ah, bl, acc[c], 0, 0, 0);
        }
    }

    float asv[8], adv[8];
    #pragma unroll
    for (int c = 0; c < 8; ++c) {
        asv[c] = a_s[c * 16 + nl];
        adv[c] = a_d[c * 16 + nl];
    }
    int Rb = bid * 64 + wid * 16 + g * 4;
    #pragma unroll
    for (int r = 0; r < 4; ++r) {
        int R = Rb + r;
        bool ok = (R < Nrows);
        float ps = 0.f, pd = 0.f;
        #pragma unroll
        for (int c = 0; c < 8; ++c) {
            float v = acc[c][r];
            if (ok) outb[(size_t)R * 128 + c * 16 + nl] = f2bf(v);
            ps = fmaf(v, asv[c], ps);
            pd = fmaf(v, adv[c], pd);
        }
        #pragma unroll
        for (int o = 8; o; o >>= 1) {
            ps += __shfl_xor(ps, o);
            pd += __shfl_xor(pd, o);
        }
        if (ok && nl == 0) {
            as_[R] = ps;
            ad_[R] = pd;
        }
    }
}

// ---- csr body: per-bucket fine pass -> rowptr + esrc (self-loop last) ----
// LDS provided via aliased buffer (5 KB used).
static __device__ __forceinline__ void csr_body(int* lds,
                                                const unsigned int* __restrict__ rec,
                                                const int* __restrict__ bcount,
                                                int* __restrict__ rowptr,
                                                int* __restrict__ esrc,
                                                int Nn, int nbuk, int Etot, int b) {
    int* sA  = lds;
    int* lbc = lds + THREADS;
    int* cnt = lds + 2 * THREADS;
    int* s   = lds + 3 * THREADS;
    int* cur = lds + 4 * THREADS;
    int tid = threadIdx.x;
    int v = (tid < nbuk) ? bcount[tid] : 0;
    lbc[tid] = v;
    sA[tid] = v;
    __syncthreads();
    for (int off = 1; off < THREADS; off <<= 1) {
        int t = (tid >= off) ? sA[tid - off] : 0;
        __syncthreads();
        sA[tid] += t;
        __syncthreads();
    }
    sA[tid] -= v;                   // exclusive scan = sbase[tid]
    __syncthreads();
    int n0 = b * BUK_S;
    int ns = min(BUK_S, Nn - n0);
    int cnt_e = lbc[b];
    int rbase = sA[b];
    int cb = rbase + b * BUK_S;     // cbase

    cnt[tid] = 0;
    __syncthreads();
    for (int i = tid; i < cnt_e; i += THREADS)
        atomicAdd(&cnt[rec[rbase + i] >> 17], 1);
    __syncthreads();
    int w = (tid < ns) ? cnt[tid] + 1 : 0;   // +1 self-loop
    s[tid] = w;
    __syncthreads();
    for (int off = 1; off < THREADS; off <<= 1) {
        int t = (tid >= off) ? s[tid - off] : 0;
        __syncthreads();
        s[tid] += t;
        __syncthreads();
    }
    int excl = s[tid] - w;
    __syncthreads();
    s[tid] = excl;
    cur[tid] = excl;
    if (tid < ns) rowptr[n0 + tid] = cb + excl;
    if (b == nbuk - 1 && tid == 0) rowptr[Nn] = Etot;
    __syncthreads();
    for (int i = tid; i < cnt_e; i += THREADS) {
        unsigned int r = rec[rbase + i];
        int l = r >> 17;
        int slot = atomicAdd(&cur[l], 1);
        esrc[cb + slot] = (int)(r & 0x1FFFFu);
    }
    __syncthreads();
    if (tid < ns) esrc[cb + s[tid] + cnt[tid]] = n0 + tid;   // self-loop last
}

// ---- layer-1 gemm ∥ csr (independent chains; LDS aliased, no fences) ----
__global__ __launch_bounds__(THREADS) void k_gemm_csr(const float* __restrict__ X,
                                                      const int* __restrict__ idx,
                                                      const unsigned short* __restrict__ WBh,
                                                      const unsigned short* __restrict__ WBl,
                                                      const float* __restrict__ a_s,
                                                      const float* __restrict__ a_d,
                                                      unsigned short* __restrict__ outb,
                                                      float* __restrict__ as_,
                                                      float* __restrict__ ad_,
                                                      int Nrows, int gemm_blocks,
                                                      const unsigned int* __restrict__ rec,
                                                      const int* __restrict__ bcount,
                                                      int* __restrict__ rowptr,
                                                      int* __restrict__ esrc,
                                                      int nbuk, int Etot) {
    __shared__ unsigned short smem[64 * 128];   // 16 KB, aliased by both paths
    if ((int)blockIdx.x >= gemm_blocks) {
        csr_body((int*)smem, rec, bcount, rowptr, esrc, Nrows, nbuk, Etot,
                 blockIdx.x - gemm_blocks);
        return;
    }
    gemm_body(smem, X, idx, WBh, WBl, a_s, a_d, outb, as_, ad_, Nrows, blockIdx.x);
}

// ---- plain layer-2 gemm ----
__global__ __launch_bounds__(THREADS) void k_gemm(const float* __restrict__ X,
                                                  const unsigned short* __restrict__ WBh,
                                                  const unsigned short* __restrict__ WBl,
                                                  const float* __restrict__ a_s,
                                                  const float* __restrict__ a_d,
                                                  unsigned short* __restrict__ outb,
                                                  float* __restrict__ as_,
                                                  float* __restrict__ ad_, int Nrows) {
    __shared__ unsigned short xh[64 * 128];   // 16 KB
    gemm_body(xh, X, nullptr, WBh, WBl, a_s, a_d, outb, as_, ad_, Nrows, blockIdx.x);
}

// wave per dst node, fused attention-coef + aggregation (R15/R17 form).
__global__ __launch_bounds__(THREADS) void k_agg(const unsigned short* __restrict__ hb,
                                                 const float* __restrict__ as_,
                                                 const float* __restrict__ ad_,
                                                 const int* __restrict__ rowptr,
                                                 const int* __restrict__ esrc,
                                                 const float* __restrict__ bias,
                                                 float* __restrict__ out, int Nn) {
    __shared__ int2 ep[4][64];
    int w = threadIdx.x >> 6;
    int lane = threadIdx.x & 63;
    int half = lane >> 5;    // which edge of the pair
    int j = lane & 31;       // dim group (4 dims per lane)
    int d = blockIdx.x * 4 + w;
    if (d >= Nn) return;
    int beg = rowptr[d], end = rowptr[d + 1];
    float adv = ad_[d];
    float z = 0.f, a0 = 0.f, a1 = 0.f, a2 = 0.f, a3 = 0.f;
    for (int c0 = beg; c0 < end; c0 += 64) {
        int kk = c0 + lane;
        bool ok = (kk < end);
        int sl = esrc[ok ? kk : beg];
        float pv = 0.f;
        if (ok) {
            float e = as_[sl] + adv;
            e = (e > 0.f) ? e : 0.2f * e;
            pv = __expf(e);
        }
        ep[w][lane] = make_int2(sl, __float_as_int(pv));
        int cn = end - c0;
        if (cn > 64) cn = 64;
        for (int k0 = 0; k0 < cn; k0 += 16) {
            int2 ev[8];
            #pragma unroll
            for (int i = 0; i < 8; ++i)
                ev[i] = ep[w][(k0 + 2 * i + half) & 63];   // p=0 past cn
            uint2 hv[8];
            #pragma unroll
            for (int i = 0; i < 8; ++i)
                hv[i] = *(const uint2*)&hb[((size_t)ev[i].x << 7) + j * 4];
            #pragma unroll
            for (int i = 0; i < 8; ++i) {
                float p = __int_as_float(ev[i].y);
                z += p;
                a0 += p * __uint_as_float(hv[i].x << 16);
                a1 += p * __uint_as_float(hv[i].x & 0xffff0000u);
                a2 += p * __uint_as_float(hv[i].y << 16);
                a3 += p * __uint_as_float(hv[i].y & 0xffff0000u);
            }
        }
    }
    z  += __shfl_xor(z, 32);
    a0 += __shfl_xor(a0, 32);
    a1 += __shfl_xor(a1, 32);
    a2 += __shfl_xor(a2, 32);
    a3 += __shfl_xor(a3, 32);
    if (half == 0) {
        float inv = 1.f / z;
        float4 o;
        o.x = fmaxf(a0 * inv + bias[j * 4 + 0], 0.f);
        o.y = fmaxf(a1 * inv + bias[j * 4 + 1], 0.f);
        o.z = fmaxf(a2 * inv + bias[j * 4 + 2], 0.f);
        o.w = fmaxf(a3 * inv + bias[j * 4 + 3], 0.f);
        *(float4*)&out[(size_t)d * 128 + j * 4] = o;
    }
}

// phase 1: grid (G, PSLICE); each block sums a strided slice of graph g's rows
__global__ __launch_bounds__(THREADS) void k_pool_partial(const float* __restrict__ x,
                                                          const int* __restrict__ batch,
                                                          float* __restrict__ part, int Nn) {
    int g = blockIdx.x;
    int s = blockIdx.y;
    int a = 0, b = Nn;
    while (a < b) { int mid = (a + b) >> 1; if (batch[mid] < g) a = mid + 1; else b = mid; }
    int lo = a;
    b = Nn;
    while (a < b) { int mid = (a + b) >> 1; if (batch[mid] < g + 1) a = mid + 1; else b = mid; }
    int hi = a;

    int j = threadIdx.x & 127;
    int half = threadIdx.x >> 7;
    float acc = 0.f;
    for (int n = lo + s * 2 + half; n < hi; n += 2 * PSLICE) acc += x[(size_t)n * 128 + j];
    __shared__ float sred[THREADS];
    sred[threadIdx.x] = acc;
    __syncthreads();
    if (half == 0) part[((size_t)g * PSLICE + s) * 128 + j] = sred[j] + sred[128 + j];
}

// phase 2: one block (128 threads) per graph: reduce partials, mean, logits
__global__ __launch_bounds__(128) void k_pool_final(const float* __restrict__ part,
                                                    const int* __restrict__ batch,
                                                    const float* __restrict__ Wc,
                                                    const float* __restrict__ bc,
                                                    float* __restrict__ out, int Nn, int Gn) {
    int g = blockIdx.x;
    int j = threadIdx.x;
    int a = 0, b = Nn;
    while (a < b) { int mid = (a + b) >> 1; if (batch[mid] < g) a = mid + 1; else b = mid; }
    int lo = a;
    b = Nn;
    while (a < b) { int mid = (a + b) >> 1; if (batch[mid] < g + 1) a = mid + 1; else b = mid; }
    int cnt = a - lo;

    float s = 0.f;
    #pragma unroll
    for (int t = 0; t < PSLICE; ++t) s += part[((size_t)g * PSLICE + t) * 128 + j];
    float mean = s / fmaxf((float)cnt, 1.f);
    out[Gn + (size_t)g * 128 + j] = mean;

    __shared__ float sred[128];
    sred[j] = mean * Wc[j];
    __syncthreads();
    for (int off = 64; off >= 1; off >>= 1) {
        if (j < off) sred[j] += sred[j + off];
        __syncthreads();
    }
    if (j == 0) out[g] = sred[0] + bc[0];
}

static inline size_t align256(size_t x) { return (x + 255) & ~(size_t)255; }

extern "C" void kernel_launch(void* const* d_in, const int* in_sizes, int n_in,
                              void* d_out, int out_size, void* d_ws, size_t ws_size,
                              hipStream_t stream) {
    const int* x_lex = (const int*)d_in[0];
    const int* eidx  = (const int*)d_in[1];
    const int* batch = (const int*)d_in[2];
    const float* emb = (const float*)d_in[3];
    const float* W1  = (const float*)d_in[4];
    const float* a_s1 = (const float*)d_in[5];
    const float* a_d1 = (const float*)d_in[6];
    const float* b1  = (const float*)d_in[7];
    const float* W2  = (const float*)d_in[8];
    const float* a_s2 = (const float*)d_in[9];
    const float* a_d2 = (const float*)d_in[10];
    const float* b2  = (const float*)d_in[11];
    const float* Wc  = (const float*)d_in[12];
    const float* bc  = (const float*)d_in[13];

    const int N = in_sizes[0];
    const int E = in_sizes[1] / 2;
    const int G = out_size / 129;      // out = [G logits] + [G x 128 pool]
    const int Etot = E + N;
    const int* esrc_in = eidx;
    const int* edst_in = eidx + E;
    const int NBUK = (N + BUK_S - 1) / BUK_S;   // 256 for N=50000

    // workspace carve
    char* p = (char*)d_ws;
    unsigned short* hb = (unsigned short*)p;  p += align256((size_t)N * 128 * 2);
    float* obuf = (float*)p;            p += align256((size_t)N * 128 * 4);
    float* as_  = (float*)p;            p += align256((size_t)N * 4);
    float* ad_  = (float*)p;            p += align256((size_t)N * 4);
    int* bhist  = (int*)p;              p += align256((size_t)SORT_BLOCKS * THREADS * 4);
    int* bcount = (int*)p;              p += align256((size_t)THREADS * 4);
    int* rowptr = (int*)p;              p += align256((size_t)(N + 1) * 4);
    unsigned int* rec = (unsigned int*)p; p += align256((size_t)Etot * 4);
    int* esrc   = (int*)p;              p += align256((size_t)Etot * 4);
    float* part = (float*)p;            p += align256((size_t)G * PSLICE * 128 * 4);
    unsigned short* WBh1 = (unsigned short*)p; p += align256((size_t)128 * 128 * 2);
    unsigned short* WBl1 = (unsigned short*)p; p += align256((size_t)128 * 128 * 2);
    unsigned short* WBh2 = (unsigned short*)p; p += align256((size_t)128 * 128 * 2);
    unsigned short* WBl2 = (unsigned short*)p; p += align256((size_t)128 * 128 * 2);

    const int chunk = (E + SORT_BLOCKS - 1) / SORT_BLOCKS;
    const int gemm_grid = (N + 63) / 64;
    const int agg_grid = (N + 3) / 4;

    // 1. prep: W split ∥ bucket hist
    k_prep<<<128 + SORT_BLOCKS, THREADS, 0, stream>>>(W1, W2, WBh1, WBl1, WBh2, WBl2,
                                                      edst_in, bhist, E, chunk);

    // 2. coarse scatter
    k_bukscatter<<<SORT_BLOCKS, THREADS, 0, stream>>>(esrc_in, edst_in, bhist, bcount, rec, E, chunk);

    // 3. layer-1 gemm ∥ csr fine pass
    k_gemm_csr<<<gemm_grid + NBUK, THREADS, 0, stream>>>(
        emb, x_lex, WBh1, WBl1, a_s1, a_d1, hb, as_, ad_, N, gemm_grid,
        rec, bcount, rowptr, esrc, NBUK, Etot);

    // 4. layer-1 agg
    k_agg<<<agg_grid, THREADS, 0, stream>>>(hb, as_, ad_, rowptr, esrc, b1, obuf, N);

    // 5-6. layer 2
    k_gemm<<<gemm_grid, THREADS, 0, stream>>>(obuf, WBh2, WBl2, a_s2, a_d2, hb, as_, ad_, N);
    k_agg<<<agg_grid, THREADS, 0, stream>>>(hb, as_, ad_, rowptr, esrc, b2, obuf, N);

    // 7-8. pool + logits
    k_pool_partial<<<dim3(G, PSLICE), THREADS, 0, stream>>>(obuf, batch, part, N);
    k_pool_final<<<G, 128, 0, stream>>>(part, batch, Wc, bc, (float*)d_out, N, G);
}